// Round 8
// baseline (87.197 us; speedup 1.0000x reference)
//
#include <hip/hip_runtime.h>
#include <hip/hip_bf16.h>

// out[n,h,i,j] = logits[i][ clamp(j-i+512, 1, 1023) ],  logits = Q @ R  (per n,h)
// n=4 h=16 L=1024 d=64, table width 1025.
//
// R8 = R7 minus nontemporal stores (single isolated change).
//   - GEMM: direct R gathers, swapped-operand MFMA, acc packed to bf16, ds_write_b64
//   - writer: aligned b64-pair LDS reads + wave-uniform shift select, bf16->f32 via <<16,
//     PLAIN f32x4 output stores (L2 write-combining path, like the 6.9 TB/s memsets)

#define NH 16
#define LQ 1024
#define DD 64
#define TT 1025
#define MAXP 512
#define PADS 4          // left pad in shorts (multiple of 4 keeps 8B alignment)
#define LSTRIDE2 1036   // shorts; row stride 2072 B

typedef float f32x4 __attribute__((ext_vector_type(4)));
typedef short s16x4 __attribute__((ext_vector_type(4)));
typedef short s16x8 __attribute__((ext_vector_type(8)));

__device__ __forceinline__ short f2bf(float f) {
    __hip_bfloat16 h = __float2bfloat16(f);   // RNE
    return __builtin_bit_cast(short, h);
}
__device__ __forceinline__ float bf2f(short s) {
    return __builtin_bit_cast(float, ((unsigned)(unsigned short)s) << 16);
}

// Writer helper: D = wave-uniform misalignment ((512 - i) & 3), compile-time.
template<int D>
__device__ __forceinline__ void write_chunks(const unsigned short* __restrict__ lrow,
                                             float p1, float p2,
                                             int i, int l, float* __restrict__ orow) {
    #pragma unroll
    for (int c = 0; c < 4; ++c) {
        const int j0 = c * 256 + 4 * l;
        const int t0 = j0 - i + MAXP;
        int colA = PADS + t0 - D;                 // = PADS + (t0 & ~3), 8B aligned
        colA = colA < 0 ? 0 : (colA > PADS + LQ ? PADS + LQ : colA);  // clamped lanes: value unused
        s16x4 A = *(const s16x4*)(lrow + colA);
        s16x4 B = {0, 0, 0, 0};
        if (D) B = *(const s16x4*)(lrow + colA + 4);
        f32x4 v;
        #pragma unroll
        for (int e = 0; e < 4; ++e) {
            const int t = t0 + e;
            const float in = bf2f((D + e < 4) ? A[D + e] : B[D + e - 4]);
            v[e] = t < 1 ? p1 : (t > LQ - 1 ? p2 : in);
        }
        *(f32x4*)(orow + j0) = v;                 // plain store (no nt)
    }
}

// grid (ib=64, nh=64), block 256 = 4 waves; block = 16 i-rows x all 1024 t.
__global__ __launch_bounds__(256, 4) void lpb_fused(const float* __restrict__ Q,
                                                    const float* __restrict__ R,
                                                    float* __restrict__ out) {
    __shared__ unsigned short lg[16][LSTRIDE2];   // bf16 logits, 33.2 KB

    const int ib  = blockIdx.x;
    const int nh  = blockIdx.y;
    const int h   = nh & (NH - 1);
    const int tid = threadIdx.x;
    const int w   = tid >> 6, l = tid & 63;
    const int n   = l & 15, g = l >> 4;
    const int ibase = ib * 16;

    // Q fragment (op1/B of swapped MFMA): lane (n,g) holds Q[ibase+n][kh*32 + 8g + r]
    const float* qrow = Q + ((size_t)nh * LQ + (ibase + n)) * DD + 8 * g;
    s16x8 qf[2];
    #pragma unroll
    for (int kh = 0; kh < 2; ++kh) {
        f32x4 a = *(const f32x4*)(qrow + kh * 32);
        f32x4 b = *(const f32x4*)(qrow + kh * 32 + 4);
        #pragma unroll
        for (int r = 0; r < 4; ++r) { qf[kh][r] = f2bf(a[r]); qf[kh][4 + r] = f2bf(b[r]); }
    }

    // GEMM: wave w covers t in [256w, 256w+256), 16 tiles of 16 t, K=64
    const float* rbase = R + (size_t)(h * DD + 8 * g) * TT;
    #pragma unroll 4
    for (int mt = 0; mt < 16; ++mt) {
        const int tb = w * 256 + mt * 16;
        const float* rc = rbase + tb + n;
        s16x8 rf0, rf1;   // A: lane (n,g) holds R[h][8g+r][tb+n]  (row = t-local = n)
        #pragma unroll
        for (int r = 0; r < 8; ++r) {
            rf0[r] = f2bf(rc[(size_t)r * TT]);
            rf1[r] = f2bf(rc[(size_t)(32 + r) * TT]);
        }
        f32x4 acc = (f32x4){0.f, 0.f, 0.f, 0.f};
        acc = __builtin_amdgcn_mfma_f32_16x16x32_bf16(rf0, qf[0], acc, 0, 0, 0);
        acc = __builtin_amdgcn_mfma_f32_16x16x32_bf16(rf1, qf[1], acc, 0, 0, 0);
        // D: col = n -> i-local row, row = 4g+s -> t = tb+4g+s: pack to bf16, b64 write
        s16x4 hv;
        #pragma unroll
        for (int s = 0; s < 4; ++s) hv[s] = f2bf(acc[s]);
        *(s16x4*)&lg[n][PADS + tb + 4 * g] = hv;
    }
    __syncthreads();

    // writer: wave w emits rows 4w..4w+3 as full aligned 4KB rows
    #pragma unroll
    for (int rr = 0; rr < 4; ++rr) {
        const int il = 4 * w + rr;
        const int i  = ibase + il;
        const unsigned short* lrow = &lg[il][0];
        const float p1 = bf2f(lrow[PADS + 1]);          // left clamp constant
        const float p2 = bf2f(lrow[PADS + LQ - 1]);     // right clamp constant
        float* orow = out + ((size_t)nh * LQ + i) * LQ;
        switch ((MAXP - i) & 3) {                       // row-uniform shift
            case 0: write_chunks<0>(lrow, p1, p2, i, l, orow); break;
            case 1: write_chunks<1>(lrow, p1, p2, i, l, orow); break;
            case 2: write_chunks<2>(lrow, p1, p2, i, l, orow); break;
            default: write_chunks<3>(lrow, p1, p2, i, l, orow); break;
        }
    }
}

extern "C" void kernel_launch(void* const* d_in, const int* in_sizes, int n_in,
                              void* d_out, int out_size, void* d_ws, size_t ws_size,
                              hipStream_t stream) {
    const float* Q = (const float*)d_in[0];
    const float* R = (const float*)d_in[1];
    float* out = (float*)d_out;

    lpb_fused<<<dim3(64, 64), 256, 0, stream>>>(Q, R, out);
}

// Round 9
// 84.051 us; speedup vs baseline: 1.0374x; 1.0374x over previous
//
#include <hip/hip_runtime.h>
#include <hip/hip_bf16.h>

// out[n,h,i,j] = logits[i][ clamp(j-i+512, 1, 1023) ],  logits = Q @ R  (per n,h)
// n=4 h=16 L=1024 d=64, table width 1025.
//
// R9: barrier-free streaming. Each WAVE owns 16 i-rows x all t, with a wave-private
// bf16 ring buffer (288 t-slots) in LDS. Per output chunk c (256 j), compute t-tiles
// until the needed window [256c-base+497, 256c-base+767] is resident, then emit the
// chunk with nt stores. No __syncthreads anywhere; stores spread evenly in time.
// Waves with high base skip never-needed high-t tiles. XCD swizzle: 8 heads per XCD.

#define NH 16
#define LQ 1024
#define DD 64
#define TT 1025
#define MAXP 512
#define RING 288
#define RSTRIDE 296    // shorts; 592 B row stride -> ds_write_b64 2-way (free)

typedef float f32x4 __attribute__((ext_vector_type(4)));
typedef short s16x4 __attribute__((ext_vector_type(4)));
typedef short s16x8 __attribute__((ext_vector_type(8)));

__device__ __forceinline__ short f2bf(float f) {
    __hip_bfloat16 h = __float2bfloat16(f);   // RNE
    return __builtin_bit_cast(short, h);
}
__device__ __forceinline__ float bf2f(unsigned short s) {
    return __builtin_bit_cast(float, ((unsigned)s) << 16);
}
__device__ __forceinline__ int mod288(int x) {  // x in [0, 1020]
    return x >= 864 ? x - 864 : (x >= 576 ? x - 576 : (x >= 288 ? x - 288 : x));
}

// Emit one 1KB chunk of one output row. D = (512 - i) & 3, compile-time.
template<int D>
__device__ __forceinline__ void write_row(const unsigned short* __restrict__ lrow,
                                          int i, int c, int l,
                                          float* __restrict__ orow) {
    const float p1 = bf2f(lrow[1]);            // logits[i][1]    (left clamp)
    const float p2 = bf2f(lrow[159]);          // logits[i][1023] (right clamp; 1023%288)
    const int j0 = c * 256 + 4 * l;
    const int t0 = j0 - i + MAXP;
    const int tA = t0 - D;                     // 4-aligned window base
    int a = tA;     a = a < 0 ? 0 : (a > 1020 ? 1020 : a);
    int b = tA + 4; b = b < 0 ? 0 : (b > 1020 ? 1020 : b);
    const s16x4 A = *(const s16x4*)(lrow + mod288(a));
    const s16x4 B = *(const s16x4*)(lrow + mod288(b));
    f32x4 v;
    #pragma unroll
    for (int e = 0; e < 4; ++e) {
        const int t = t0 + e;
        const short in = (D + e < 4) ? A[D + e] : B[D + e - 4];
        v[e] = t < 1 ? p1 : (t > LQ - 1 ? p2 : bf2f((unsigned short)in));
    }
    __builtin_nontemporal_store(v, (f32x4*)(orow + j0));
}

// grid 1024 blocks x 256 thr (4 independent waves). Wave = 16 rows x all t.
__global__ __launch_bounds__(256, 4) void lpb_stream(const float* __restrict__ Q,
                                                     const float* __restrict__ R,
                                                     float* __restrict__ out) {
    __shared__ unsigned short lg[4][16][RSTRIDE];   // 37.9 KB -> 4 blocks/CU

    // XCD swizzle: blocks b = k (mod 8) -> heads [8k, 8k+8): R+Q slices L2-resident
    const int bidx = blockIdx.x;
    const int swz  = (bidx & 7) * 128 + (bidx >> 3);
    const int nh   = swz >> 4;
    const int rg   = swz & 15;
    const int h    = nh & (NH - 1);

    const int tid = threadIdx.x;
    const int w = tid >> 6, l = tid & 63;
    const int n = l & 15, g = l >> 4;
    const int base = rg * 64 + w * 16;              // this wave's first row
    unsigned short (*ring)[RSTRIDE] = lg[w];

    // Q fragment (B-operand): lane (n,g) holds Q[base+n][kh*32 + 8g + r]
    const float* qrow = Q + ((size_t)nh * LQ + (base + n)) * DD + 8 * g;
    s16x8 qf[2];
    #pragma unroll
    for (int kh = 0; kh < 2; ++kh) {
        f32x4 a = *(const f32x4*)(qrow + kh * 32);
        f32x4 b = *(const f32x4*)(qrow + kh * 32 + 4);
        #pragma unroll
        for (int r = 0; r < 4; ++r) { qf[kh][r] = f2bf(a[r]); qf[kh][4 + r] = f2bf(b[r]); }
    }

    const float* rbase = R + (size_t)(h * DD + 8 * g) * TT;
    float* obase = out + (size_t)nh * LQ * LQ;

    int computed = 0;   // t-tiles done
    int ringc = 0;      // ring col (shorts) of next tile, wave-uniform

    #pragma unroll 1
    for (int c = 0; c < 4; ++c) {
        // tiles needed before this chunk: t <= Thi = 256c + 767 - base
        const int Thi = 256 * c + 767 - base;
        int need = (Thi + 16) >> 4;
        need = need < 1 ? 1 : (need > 64 ? 64 : need);

        #pragma unroll 1
        for (; computed < need; ++computed) {
            const int tb = computed << 4;
            const float* rc = rbase + tb + n;
            s16x8 rf0, rf1;   // A-operand: lane (n,g) holds R[h][8g+r][tb+n]
            #pragma unroll
            for (int r = 0; r < 8; ++r) {
                rf0[r] = f2bf(rc[(size_t)r * TT]);
                rf1[r] = f2bf(rc[(size_t)(32 + r) * TT]);
            }
            f32x4 acc = (f32x4){0.f, 0.f, 0.f, 0.f};
            acc = __builtin_amdgcn_mfma_f32_16x16x32_bf16(rf0, qf[0], acc, 0, 0, 0);
            acc = __builtin_amdgcn_mfma_f32_16x16x32_bf16(rf1, qf[1], acc, 0, 0, 0);
            // D: col=n -> i-local row, row=4g+s -> t=tb+4g+s; pack bf16, b64 ring write
            s16x4 hv;
            #pragma unroll
            for (int s = 0; s < 4; ++s) hv[s] = f2bf(acc[s]);
            *(s16x4*)&ring[n][ringc + 4 * g] = hv;
            ringc += 16; if (ringc == RING) ringc = 0;
        }

        // emit chunk c for all 16 rows, grouped by store shift D = (512-i)&3
        #pragma unroll 1
        for (int q = 0; q < 4; ++q) {
            { const int rr = ((2048 + MAXP - base - 0) & 3) + 4 * q; const int i = base + rr;
              write_row<0>(&ring[rr][0], i, c, l, obase + (size_t)i * LQ); }
            { const int rr = ((2048 + MAXP - base - 1) & 3) + 4 * q; const int i = base + rr;
              write_row<1>(&ring[rr][0], i, c, l, obase + (size_t)i * LQ); }
            { const int rr = ((2048 + MAXP - base - 2) & 3) + 4 * q; const int i = base + rr;
              write_row<2>(&ring[rr][0], i, c, l, obase + (size_t)i * LQ); }
            { const int rr = ((2048 + MAXP - base - 3) & 3) + 4 * q; const int i = base + rr;
              write_row<3>(&ring[rr][0], i, c, l, obase + (size_t)i * LQ); }
        }
    }
}

extern "C" void kernel_launch(void* const* d_in, const int* in_sizes, int n_in,
                              void* d_out, int out_size, void* d_ws, size_t ws_size,
                              hipStream_t stream) {
    const float* Q = (const float*)d_in[0];
    const float* R = (const float*)d_in[1];
    float* out = (float*)d_out;

    lpb_stream<<<dim3(1024), 256, 0, stream>>>(Q, R, out);
}

// Round 10
// 83.387 us; speedup vs baseline: 1.0457x; 1.0080x over previous
//
#include <hip/hip_runtime.h>
#include <hip/hip_bf16.h>

// out[n,h,i,j] = logits[n,h][i][ clamp(j-i+512, 1, 1023) ],  logits = Q @ R (per n,h)
// n=4 h=16 L=1024 d=64, table width 1025.
//
// R10: batch-shared GEMM. Block = (h, 16 i-rows) x ALL 4 batches n: R fragments are
// loaded ONCE per tile (registers) and feed 4 MFMAs -> chip-wide R L2-read volume
// drops 4x (1.07 GB -> 268 MB). Logits kept as a 2-slot ring of 256-t bf16 chunks in
// LDS (64 rows = 4n x 16i); output chunks are emitted as soon as their 271-wide
// t-window is resident (schedule hand-verified for base = 0 / 512 / 1008).
// Proven elements kept: swapped-operand MFMA (b64 LDS writes), shift-select writer,
// nontemporal stores, XCD-chunked swizzle (each XCD: 2 heads -> 524 KB hot R).

#define NH 16
#define LQ 1024
#define DD 64
#define TT 1025
#define MAXP 512
#define CST 264          // shorts per lg row (256 + pad)
#define SSTR (64 * CST)  // shorts between slot0 and slot1 for same row

typedef float f32x4 __attribute__((ext_vector_type(4)));
typedef short s16x4 __attribute__((ext_vector_type(4)));
typedef short s16x8 __attribute__((ext_vector_type(8)));

__device__ __forceinline__ short f2bf(float f) {
    __hip_bfloat16 h = __float2bfloat16(f);   // RNE
    return __builtin_bit_cast(short, h);
}
__device__ __forceinline__ float bf2f(unsigned short s) {
    return __builtin_bit_cast(float, ((unsigned)s) << 16);
}

// Emit one 1KB chunk of one output row. D = (512 - i) & 3, compile-time.
// lgrow0 = &lg[0][row][0]; slot(t) = (t>>8)&1 (ring of two 256-t chunks).
template<int D>
__device__ __forceinline__ void write_row(const unsigned short* __restrict__ lgrow0,
                                          int i, int OC, int l,
                                          float* __restrict__ orow) {
    const float p1 = bf2f(lgrow0[1]);           // t=1    (slot0; valid whenever used)
    const float p2 = bf2f(lgrow0[SSTR + 255]);  // t=1023 (slot1; valid whenever used)
    const int j0 = OC * 256 + 4 * l;
    const int t0 = j0 - i + MAXP;
    const int tA = t0 - D;                      // 4-aligned
    int ta = tA     < 0 ? 0 : (tA     > 1020 ? 1020 : tA);
    int tb = tA + 4 < 0 ? 0 : (tA + 4 > 1020 ? 1020 : tA + 4);
    const s16x4 A = *(const s16x4*)(lgrow0 + ((ta >> 8) & 1) * SSTR + (ta & 255));
    s16x4 Bv = A;
    if (D) Bv = *(const s16x4*)(lgrow0 + ((tb >> 8) & 1) * SSTR + (tb & 255));
    f32x4 v;
    #pragma unroll
    for (int e = 0; e < 4; ++e) {
        const int t = t0 + e;
        const unsigned short in = (unsigned short)((D + e < 4) ? A[D + e] : Bv[D + e - 4]);
        v[e] = t < 1 ? p1 : (t > LQ - 1 ? p2 : bf2f(in));
    }
    __builtin_nontemporal_store(v, (f32x4*)(orow + j0));
}

// grid 1024 (1D), block 256 = 4 waves. Block = (h, 16 i) x 4 batches x all t.
__global__ __launch_bounds__(256, 2) void lpb_nshare(const float* __restrict__ Q,
                                                     const float* __restrict__ R,
                                                     float* __restrict__ out) {
    __shared__ unsigned short lg[2][64][CST];   // 2-slot ring, 64 rows (4n x 16i), 67.6 KB

    // XCD-chunked bijective swizzle: each XCD sees 2 heads (hot R = 524 KB)
    const int bidx = blockIdx.x;
    const int swz  = (bidx & 7) * 128 + (bidx >> 3);
    const int h    = swz >> 6;
    const int ib   = swz & 63;
    const int base = ib * 16;

    const int tid = threadIdx.x;
    const int w = tid >> 6, l = tid & 63;
    const int n = l & 15, g = l >> 4;

    // Q fragments for all 4 batches (B-operand): lane (n,g) holds Q[nn,h][base+n][kh*32+8g+r]
    s16x8 qf[4][2];
    #pragma unroll
    for (int nn = 0; nn < 4; ++nn) {
        const float* qrow = Q + ((size_t)(nn * NH + h) * LQ + (base + n)) * DD + 8 * g;
        #pragma unroll
        for (int kh = 0; kh < 2; ++kh) {
            f32x4 a = *(const f32x4*)(qrow + kh * 32);
            f32x4 b = *(const f32x4*)(qrow + kh * 32 + 4);
            #pragma unroll
            for (int r = 0; r < 4; ++r) { qf[nn][kh][r] = f2bf(a[r]); qf[nn][kh][4 + r] = f2bf(b[r]); }
        }
    }

    // needed t range: [max(1,497-base), min(1023,1535-base)] -> chunk skip bounds
    const int klo   = (base <= 240) ? 1 : 0;
    const int klast = min(3, (1535 - base) >> 8);
    int ocn = 0;   // next output chunk to emit

    #pragma unroll 1
    for (int k = klo; k <= klast; ++k) {
        // ---- compute logits chunk k (t in [256k, 256k+256)) into slot k&1
        unsigned short (*slot)[CST] = lg[k & 1];
        #pragma unroll
        for (int mt = 0; mt < 4; ++mt) {
            const int tb = (k << 8) + (w << 6) + (mt << 4);   // wave w: 4 tiles of 16 t
            const float* rc = R + (size_t)(h * DD + 8 * g) * TT + tb + n;
            s16x8 rf0, rf1;   // A-operand: lane (n,g) holds R[h][8g+r][tb+n]
            #pragma unroll
            for (int r = 0; r < 8; ++r) {
                rf0[r] = f2bf(rc[(size_t)r * TT]);
                rf1[r] = f2bf(rc[(size_t)(32 + r) * TT]);
            }
            const int col = (tb & 255) + 4 * g;
            #pragma unroll
            for (int nn = 0; nn < 4; ++nn) {    // R frags shared across 4 batches
                f32x4 acc = (f32x4){0.f, 0.f, 0.f, 0.f};
                acc = __builtin_amdgcn_mfma_f32_16x16x32_bf16(rf0, qf[nn][0], acc, 0, 0, 0);
                acc = __builtin_amdgcn_mfma_f32_16x16x32_bf16(rf1, qf[nn][1], acc, 0, 0, 0);
                // D: col=n -> i-local, row=4g+s -> t=tb+4g+s; pack bf16, b64 write
                s16x4 hv;
                #pragma unroll
                for (int s = 0; s < 4; ++s) hv[s] = f2bf(acc[s]);
                *(s16x4*)&slot[nn * 16 + n][col] = hv;
            }
        }
        __syncthreads();

        // ---- emit all output chunks whose full unclamped t-window is now resident
        int ocmax = (k == klast) ? 3 : (((k << 8) + 255 - 767 + base) >> 8);
        if (ocmax > 3) ocmax = 3;
        #pragma unroll 1
        for (; ocn <= ocmax; ++ocn) {
            // wave w owns rows [16w, 16w+16) = batch nn=w, i in [base, base+16)
            float* obase = out + (size_t)(w * NH + h) * LQ * LQ;
            #pragma unroll 1
            for (int q = 0; q < 4; ++q) {       // rows grouped by store shift D
                { const int rl = ((2048 + MAXP - base - 0) & 3) + 4 * q; const int i = base + rl;
                  write_row<0>(&lg[0][w * 16 + rl][0], i, ocn, l, obase + (size_t)i * LQ); }
                { const int rl = ((2048 + MAXP - base - 1) & 3) + 4 * q; const int i = base + rl;
                  write_row<1>(&lg[0][w * 16 + rl][0], i, ocn, l, obase + (size_t)i * LQ); }
                { const int rl = ((2048 + MAXP - base - 2) & 3) + 4 * q; const int i = base + rl;
                  write_row<2>(&lg[0][w * 16 + rl][0], i, ocn, l, obase + (size_t)i * LQ); }
                { const int rl = ((2048 + MAXP - base - 3) & 3) + 4 * q; const int i = base + rl;
                  write_row<3>(&lg[0][w * 16 + rl][0], i, ocn, l, obase + (size_t)i * LQ); }
            }
        }
        __syncthreads();   // protect ring slot reuse
    }
}

extern "C" void kernel_launch(void* const* d_in, const int* in_sizes, int n_in,
                              void* d_out, int out_size, void* d_ws, size_t ws_size,
                              hipStream_t stream) {
    const float* Q = (const float*)d_in[0];
    const float* R = (const float*)d_in[1];
    float* out = (float*)d_out;

    lpb_nshare<<<dim3(1024), 256, 0, stream>>>(Q, R, out);
}